// Round 1
// baseline (8768.388 us; speedup 1.0000x reference)
//
#include <hip/hip_runtime.h>
#include <hip/hip_bf16.h>
#include <math.h>

// Problem constants
#define B  8
#define NN 511
#define L  512          // n_transit
#define D  1024
#define DFF 4096
#define H  8
#define HD 128
#define NA 5
#define NLAYERS 4
#define ML (B*L)        // 4096 rows

__device__ __forceinline__ float gelu_exact(float v) {
    return 0.5f * v * (1.0f + erff(v * 0.70710678118654752440f));
}

// ---------------------------------------------------------------------------
// Embedding: x[b*L+t][d] = (t<511 ? ctx_embed : table[qidx]) + pos[t][d]
// ---------------------------------------------------------------------------
__global__ void embed_kernel(const float* __restrict__ states,
                             const float* __restrict__ actions,
                             const float* __restrict__ next_states,
                             const float* __restrict__ rewards,
                             const float* __restrict__ pos,
                             const float* __restrict__ ecw,   // (1024,10)
                             const float* __restrict__ ecb,   // (1024)
                             const float* __restrict__ table, // (81,1024)
                             const int*   __restrict__ qs,    // (8,2)
                             float* __restrict__ x) {
    size_t gid = (size_t)blockIdx.x * 256 + threadIdx.x;   // B*L*D threads
    int d   = (int)(gid & (D - 1));
    int row = (int)(gid >> 10);           // 0..4095
    int t = row & (L - 1);
    int b = row >> 9;
    float v;
    if (t < NN) {
        const float* w = ecw + (size_t)d * 10;
        int st = b * NN + t;
        float acc = ecb[d];
        acc += states[st*2+0]*w[0] + states[st*2+1]*w[1];
        acc += actions[st*5+0]*w[2] + actions[st*5+1]*w[3] + actions[st*5+2]*w[4]
             + actions[st*5+3]*w[5] + actions[st*5+4]*w[6];
        acc += rewards[st]*w[7];
        acc += next_states[st*2+0]*w[8] + next_states[st*2+1]*w[9];
        v = acc;
    } else {
        int qi = qs[b*2+0] * 9 + qs[b*2+1];
        v = table[(size_t)qi * D + d];
    }
    x[(size_t)row * D + d] = v + pos[(size_t)t * D + d];
}

// ---------------------------------------------------------------------------
// Generic GEMM: C[m][n] = act(sum_k A[m][k] * W[n][k] + bias[n])
// tile 64x64, 256 threads, 4x4 per thread.  ACT: 0=none, 1=gelu
// ---------------------------------------------------------------------------
template<int ACT>
__global__ void gemm_bias_kernel(const float* __restrict__ A,
                                 const float* __restrict__ W,
                                 const float* __restrict__ bias,
                                 float* __restrict__ C,
                                 int M, int N, int K) {
    __shared__ float As[16][65];
    __shared__ float Ws[16][65];
    int tidx = threadIdx.x;
    int tx = tidx & 15, ty = tidx >> 4;
    int m0 = blockIdx.y * 64, n0 = blockIdx.x * 64;
    int mrow = tidx >> 2, kq = (tidx & 3) << 2;
    float acc[4][4] = {};
    for (int k0 = 0; k0 < K; k0 += 16) {
        float4 av = *(const float4*)&A[(size_t)(m0 + mrow) * K + k0 + kq];
        float4 wv = *(const float4*)&W[(size_t)(n0 + mrow) * K + k0 + kq];
        As[kq+0][mrow] = av.x; As[kq+1][mrow] = av.y;
        As[kq+2][mrow] = av.z; As[kq+3][mrow] = av.w;
        Ws[kq+0][mrow] = wv.x; Ws[kq+1][mrow] = wv.y;
        Ws[kq+2][mrow] = wv.z; Ws[kq+3][mrow] = wv.w;
        __syncthreads();
        #pragma unroll
        for (int k = 0; k < 16; ++k) {
            float a[4], b[4];
            #pragma unroll
            for (int i = 0; i < 4; ++i) a[i] = As[k][ty*4+i];
            #pragma unroll
            for (int j = 0; j < 4; ++j) b[j] = Ws[k][tx*4+j];
            #pragma unroll
            for (int i = 0; i < 4; ++i)
                #pragma unroll
                for (int j = 0; j < 4; ++j)
                    acc[i][j] = fmaf(a[i], b[j], acc[i][j]);
        }
        __syncthreads();
    }
    #pragma unroll
    for (int i = 0; i < 4; ++i) {
        #pragma unroll
        for (int j = 0; j < 4; ++j) {
            float v = acc[i][j] + bias[n0 + tx*4 + j];
            if (ACT == 1) v = gelu_exact(v);
            C[(size_t)(m0 + ty*4 + i) * N + n0 + tx*4 + j] = v;
        }
    }
}

// ---------------------------------------------------------------------------
// Attention scores: per z=(b*8+h): C(512,512) = (Q Kt) * 1/sqrt(128)
// Q,K rows strided 3072 inside qkv buffer.
// ---------------------------------------------------------------------------
__global__ void attn_scores_kernel(const float* __restrict__ qkv,
                                   float* __restrict__ attnL) {
    int z = blockIdx.z; int b = z >> 3, h = z & 7;
    const float* Aq = qkv + (size_t)b * L * (3*D) + h * HD;        // Q
    const float* Bk = Aq + D;                                       // K
    float* C = attnL + (size_t)z * L * L;
    int tidx = threadIdx.x;
    int tx = tidx & 15, ty = tidx >> 4;
    int i0 = blockIdx.y * 64, j0 = blockIdx.x * 64;
    int mrow = tidx >> 2, kq = (tidx & 3) << 2;
    __shared__ float As[16][65];
    __shared__ float Bs[16][65];
    float acc[4][4] = {};
    for (int k0 = 0; k0 < HD; k0 += 16) {
        float4 av = *(const float4*)&Aq[(size_t)(i0 + mrow) * (3*D) + k0 + kq];
        float4 bv = *(const float4*)&Bk[(size_t)(j0 + mrow) * (3*D) + k0 + kq];
        As[kq+0][mrow] = av.x; As[kq+1][mrow] = av.y;
        As[kq+2][mrow] = av.z; As[kq+3][mrow] = av.w;
        Bs[kq+0][mrow] = bv.x; Bs[kq+1][mrow] = bv.y;
        Bs[kq+2][mrow] = bv.z; Bs[kq+3][mrow] = bv.w;
        __syncthreads();
        #pragma unroll
        for (int k = 0; k < 16; ++k) {
            float a[4], b2[4];
            #pragma unroll
            for (int i = 0; i < 4; ++i) a[i] = As[k][ty*4+i];
            #pragma unroll
            for (int j = 0; j < 4; ++j) b2[j] = Bs[k][tx*4+j];
            #pragma unroll
            for (int i = 0; i < 4; ++i)
                #pragma unroll
                for (int j = 0; j < 4; ++j)
                    acc[i][j] = fmaf(a[i], b2[j], acc[i][j]);
        }
        __syncthreads();
    }
    const float scale = 0.08838834764831844f;   // 1/sqrt(128)
    #pragma unroll
    for (int i = 0; i < 4; ++i)
        #pragma unroll
        for (int j = 0; j < 4; ++j)
            C[(size_t)(i0 + ty*4 + i) * L + j0 + tx*4 + j] = acc[i][j] * scale;
}

// ---------------------------------------------------------------------------
// Row softmax in place over 512 elements, one block per row
// ---------------------------------------------------------------------------
__global__ void softmax_kernel(float* __restrict__ p) {
    size_t row = blockIdx.x;
    float* r = p + row * L;
    int t = threadIdx.x;
    float a = r[t], b = r[t + 256];
    __shared__ float red[256];
    red[t] = fmaxf(a, b);
    __syncthreads();
    for (int s = 128; s > 0; s >>= 1) {
        if (t < s) red[t] = fmaxf(red[t], red[t+s]);
        __syncthreads();
    }
    float m = red[0];
    __syncthreads();
    float e0 = expf(a - m), e1 = expf(b - m);
    red[t] = e0 + e1;
    __syncthreads();
    for (int s = 128; s > 0; s >>= 1) {
        if (t < s) red[t] += red[t+s];
        __syncthreads();
    }
    float inv = 1.0f / red[0];
    r[t] = e0 * inv;
    r[t + 256] = e1 * inv;
}

// ---------------------------------------------------------------------------
// PV: per z=(b*8+h): C(512,128) = attn(512,512) @ V(512,128); V strided 3072
// C written into ctx buffer (4096,1024) at col h*128
// ---------------------------------------------------------------------------
__global__ void attn_av_kernel(const float* __restrict__ attnL,
                               const float* __restrict__ qkv,
                               float* __restrict__ ctx) {
    int z = blockIdx.z; int b = z >> 3, h = z & 7;
    const float* A  = attnL + (size_t)z * L * L;
    const float* Bv = qkv + (size_t)b * L * (3*D) + 2*D + h * HD;
    float* C = ctx + (size_t)b * L * D + h * HD;
    int tidx = threadIdx.x;
    int tx = tidx & 15, ty = tidx >> 4;
    int i0 = blockIdx.y * 64, j0 = blockIdx.x * 64;
    int arow = tidx >> 2, akq = (tidx & 3) << 2;
    int bk = tidx >> 4, bjq = (tidx & 15) << 2;
    __shared__ float As[16][65];
    __shared__ float Bs[16][65];
    float acc[4][4] = {};
    for (int k0 = 0; k0 < L; k0 += 16) {
        float4 av = *(const float4*)&A[(size_t)(i0 + arow) * L + k0 + akq];
        float4 bv = *(const float4*)&Bv[(size_t)(k0 + bk) * (3*D) + j0 + bjq];
        As[akq+0][arow] = av.x; As[akq+1][arow] = av.y;
        As[akq+2][arow] = av.z; As[akq+3][arow] = av.w;
        Bs[bk][bjq+0] = bv.x; Bs[bk][bjq+1] = bv.y;
        Bs[bk][bjq+2] = bv.z; Bs[bk][bjq+3] = bv.w;
        __syncthreads();
        #pragma unroll
        for (int k = 0; k < 16; ++k) {
            float a[4], b2[4];
            #pragma unroll
            for (int i = 0; i < 4; ++i) a[i] = As[k][ty*4+i];
            #pragma unroll
            for (int j = 0; j < 4; ++j) b2[j] = Bs[k][tx*4+j];
            #pragma unroll
            for (int i = 0; i < 4; ++i)
                #pragma unroll
                for (int j = 0; j < 4; ++j)
                    acc[i][j] = fmaf(a[i], b2[j], acc[i][j]);
        }
        __syncthreads();
    }
    #pragma unroll
    for (int i = 0; i < 4; ++i)
        #pragma unroll
        for (int j = 0; j < 4; ++j)
            C[(size_t)(i0 + ty*4 + i) * D + j0 + tx*4 + j] = acc[i][j];
}

// ---------------------------------------------------------------------------
// Fused residual add + LayerNorm: out = LN(x + y) * g + b, one block per row
// ---------------------------------------------------------------------------
__global__ void ln_add_kernel(const float* __restrict__ xin,
                              const float* __restrict__ yin,
                              float* __restrict__ xout,
                              const float* __restrict__ g,
                              const float* __restrict__ bta) {
    int row = blockIdx.x;
    int t = threadIdx.x;
    const float* xr = xin + (size_t)row * D;
    const float* yr = yin + (size_t)row * D;
    float4 xv = *(const float4*)&xr[t*4];
    float4 yv = *(const float4*)&yr[t*4];
    float s0 = xv.x + yv.x, s1 = xv.y + yv.y, s2 = xv.z + yv.z, s3 = xv.w + yv.w;
    __shared__ float red[256];
    red[t] = s0 + s1 + s2 + s3;
    __syncthreads();
    for (int st = 128; st > 0; st >>= 1) {
        if (t < st) red[t] += red[t+st];
        __syncthreads();
    }
    float mean = red[0] * (1.0f / (float)D);
    __syncthreads();
    float d0 = s0 - mean, d1 = s1 - mean, d2 = s2 - mean, d3 = s3 - mean;
    red[t] = d0*d0 + d1*d1 + d2*d2 + d3*d3;
    __syncthreads();
    for (int st = 128; st > 0; st >>= 1) {
        if (t < st) red[t] += red[t+st];
        __syncthreads();
    }
    float rstd = rsqrtf(red[0] * (1.0f / (float)D) + 1e-5f);
    float4 gv = *(const float4*)&g[t*4];
    float4 bv = *(const float4*)&bta[t*4];
    float4 o;
    o.x = d0 * rstd * gv.x + bv.x;
    o.y = d1 * rstd * gv.y + bv.y;
    o.z = d2 * rstd * gv.z + bv.z;
    o.w = d3 * rstd * gv.w + bv.w;
    *(float4*)&(xout + (size_t)row * D)[t*4] = o;
}

// ---------------------------------------------------------------------------
// Head: logits[b][a] = dot(x[b*L+511], pred_w[a]) + pred_b[a]
// ---------------------------------------------------------------------------
__global__ void logits_kernel(const float* __restrict__ x,
                              const float* __restrict__ pw,
                              const float* __restrict__ pb,
                              float* __restrict__ lbuf) {
    int ba = blockIdx.x;           // 0..39
    int b = ba / NA, a = ba % NA;
    const float* xr = x + ((size_t)(b * L + (L-1))) * D;
    const float* wr = pw + (size_t)a * D;
    float s = 0.f;
    for (int k = threadIdx.x; k < D; k += 256) s += xr[k] * wr[k];
    __shared__ float red[256];
    int t = threadIdx.x;
    red[t] = s;
    __syncthreads();
    for (int st = 128; st > 0; st >>= 1) {
        if (t < st) red[t] += red[t+st];
        __syncthreads();
    }
    if (t == 0) lbuf[ba] = red[0] + pb[a];
}

// ---------------------------------------------------------------------------
// Loss + acc (tiny, single thread)
// ---------------------------------------------------------------------------
__global__ void loss_kernel(const float* __restrict__ lbuf,
                            const int* __restrict__ tgt,
                            float* __restrict__ out) {
    if (threadIdx.x != 0 || blockIdx.x != 0) return;
    float loss = 0.f, acc = 0.f;
    for (int b = 0; b < B; ++b) {
        const float* lg = lbuf + b * NA;
        float mx = lg[0]; int am = 0;
        for (int a = 1; a < NA; ++a) if (lg[a] > mx) { mx = lg[a]; am = a; }
        float se = 0.f;
        for (int a = 0; a < NA; ++a) se += expf(lg[a] - mx);
        float lse = mx + logf(se);
        float mean_lp = 0.f;
        for (int a = 0; a < NA; ++a) mean_lp += (lg[a] - lse);
        mean_lp *= (1.0f / NA);
        int tb = tgt[b];
        float nll = -(lg[tb] - lse);
        loss += 0.9f * nll - 0.1f * mean_lp;
        acc += (am == tb) ? 1.f : 0.f;
    }
    out[0] = loss * (1.0f / B);
    out[1] = acc * (1.0f / B);
}

// ---------------------------------------------------------------------------
extern "C" void kernel_launch(void* const* d_in, const int* in_sizes, int n_in,
                              void* d_out, int out_size, void* d_ws, size_t ws_size,
                              hipStream_t stream) {
    const float* states      = (const float*)d_in[0];
    const float* actions     = (const float*)d_in[1];
    const float* next_states = (const float*)d_in[2];
    const float* rewards     = (const float*)d_in[3];
    const float* pos         = (const float*)d_in[4];
    const float* ecw         = (const float*)d_in[5];
    const float* ecb         = (const float*)d_in[6];
    const float* table       = (const float*)d_in[7];
    const float* in_proj_w   = (const float*)d_in[8];
    const float* in_proj_b   = (const float*)d_in[9];
    const float* out_proj_w  = (const float*)d_in[10];
    const float* out_proj_b  = (const float*)d_in[11];
    const float* linear1_w   = (const float*)d_in[12];
    const float* linear1_b   = (const float*)d_in[13];
    const float* linear2_w   = (const float*)d_in[14];
    const float* linear2_b   = (const float*)d_in[15];
    const float* norm1_g     = (const float*)d_in[16];
    const float* norm1_b     = (const float*)d_in[17];
    const float* norm2_g     = (const float*)d_in[18];
    const float* norm2_b     = (const float*)d_in[19];
    const float* pred_w      = (const float*)d_in[20];
    const float* pred_b      = (const float*)d_in[21];
    const int*   query_states   = (const int*)d_in[22];
    const int*   target_actions = (const int*)d_in[23];

    float* out = (float*)d_out;

    // workspace layout (floats)
    float* x    = (float*)d_ws;                      // 4096*1024
    float* buf1 = x    + (size_t)ML * D;             // 4096*3072 (qkv / proj tmp)
    float* buf2 = buf1 + (size_t)ML * (3*D);         // 4096*1024 (ctx)
    float* buf3 = buf2 + (size_t)ML * D;             // 4096*4096 (ff)
    float* lbuf = buf3 + (size_t)ML * DFF;           // 40 logits

    embed_kernel<<<(ML * D) / 256, 256, 0, stream>>>(
        states, actions, next_states, rewards, pos, ecw, ecb, table,
        query_states, x);

    for (int l = 0; l < NLAYERS; ++l) {
        float* attnL = out + 2 + (size_t)l * B * H * L * L;

        // qkv = x @ in_proj_w^T + b     (4096,3072)
        gemm_bias_kernel<0><<<dim3((3*D)/64, ML/64), 256, 0, stream>>>(
            x, in_proj_w, in_proj_b, buf1, ML, 3*D, D);
        // raw scores into attn output slice
        attn_scores_kernel<<<dim3(L/64, L/64, B*H), 256, 0, stream>>>(buf1, attnL);
        // softmax in place
        softmax_kernel<<<B*H*L, 256, 0, stream>>>(attnL);
        // ctx = attn @ v                (4096,1024)
        attn_av_kernel<<<dim3(HD/64, L/64, B*H), 256, 0, stream>>>(attnL, buf1, buf2);
        // out_proj
        gemm_bias_kernel<0><<<dim3(D/64, ML/64), 256, 0, stream>>>(
            buf2, out_proj_w, out_proj_b, buf1, ML, D, D);
        // x = LN(x + proj)
        ln_add_kernel<<<ML, 256, 0, stream>>>(x, buf1, x, norm1_g, norm1_b);
        // ff1 + gelu
        gemm_bias_kernel<1><<<dim3(DFF/64, ML/64), 256, 0, stream>>>(
            x, linear1_w, linear1_b, buf3, ML, DFF, D);
        // ff2
        gemm_bias_kernel<0><<<dim3(D/64, ML/64), 256, 0, stream>>>(
            buf3, linear2_w, linear2_b, buf1, ML, D, DFF);
        // x = LN(x + ff)
        ln_add_kernel<<<ML, 256, 0, stream>>>(x, buf1, x, norm2_g, norm2_b);
    }

    logits_kernel<<<B*NA, 256, 0, stream>>>(x, pred_w, pred_b, lbuf);
    loss_kernel<<<1, 64, 0, stream>>>(lbuf, target_actions, out);
}

// Round 2
// 1265.818 us; speedup vs baseline: 6.9271x; 6.9271x over previous
//
#include <hip/hip_runtime.h>
#include <hip/hip_bf16.h>
#include <math.h>

// Problem constants
#define B  8
#define NN 511
#define L  512          // n_transit
#define D  1024
#define DFF 4096
#define H  8
#define HD 128
#define NA 5
#define NLAYERS 4
#define ML (B*L)        // 4096 rows

typedef unsigned short u16;
typedef float f32x4 __attribute__((ext_vector_type(4)));
typedef u16   u16x8 __attribute__((ext_vector_type(8)));
typedef u16   u16x4 __attribute__((ext_vector_type(4)));
typedef __bf16 b16x8 __attribute__((ext_vector_type(8)));

__device__ __forceinline__ u16 f2bf(float f) {
    __hip_bfloat16 h = __float2bfloat16(f);
    return __builtin_bit_cast(u16, h);
}

__device__ __forceinline__ float gelu_exact(float v) {
    return 0.5f * v * (1.0f + erff(v * 0.70710678118654752440f));
}

__device__ __forceinline__ f32x4 mfma16(u16x8 a, u16x8 b, f32x4 c) {
    return __builtin_amdgcn_mfma_f32_16x16x32_bf16(
        __builtin_bit_cast(b16x8, a), __builtin_bit_cast(b16x8, b), c, 0, 0, 0);
}

__device__ __forceinline__ void gl_lds16(const u16* g, u16* l) {
    __builtin_amdgcn_global_load_lds(
        (const __attribute__((address_space(1))) unsigned int*)g,
        (__attribute__((address_space(3))) unsigned int*)l,
        16, 0, 0);
}

// ---------------------------------------------------------------------------
// Embedding: x[b*L+t][d] = (t<511 ? ctx_embed : table[qidx]) + pos[t][d]
// Writes fp32 x and bf16 x_bf.
// ---------------------------------------------------------------------------
__global__ void embed_kernel(const float* __restrict__ states,
                             const float* __restrict__ actions,
                             const float* __restrict__ next_states,
                             const float* __restrict__ rewards,
                             const float* __restrict__ pos,
                             const float* __restrict__ ecw,   // (1024,10)
                             const float* __restrict__ ecb,   // (1024)
                             const float* __restrict__ table, // (81,1024)
                             const int*   __restrict__ qs,    // (8,2)
                             float* __restrict__ x,
                             u16* __restrict__ xbf) {
    size_t gid = (size_t)blockIdx.x * 256 + threadIdx.x;   // B*L*D threads
    int d   = (int)(gid & (D - 1));
    int row = (int)(gid >> 10);           // 0..4095
    int t = row & (L - 1);
    int b = row >> 9;
    float v;
    if (t < NN) {
        const float* w = ecw + (size_t)d * 10;
        int st = b * NN + t;
        float acc = ecb[d];
        acc += states[st*2+0]*w[0] + states[st*2+1]*w[1];
        acc += actions[st*5+0]*w[2] + actions[st*5+1]*w[3] + actions[st*5+2]*w[4]
             + actions[st*5+3]*w[5] + actions[st*5+4]*w[6];
        acc += rewards[st]*w[7];
        acc += next_states[st*2+0]*w[8] + next_states[st*2+1]*w[9];
        v = acc;
    } else {
        int qi = qs[b*2+0] * 9 + qs[b*2+1];
        v = table[(size_t)qi * D + d];
    }
    float o = v + pos[(size_t)t * D + d];
    x[(size_t)row * D + d] = o;
    xbf[(size_t)row * D + d] = f2bf(o);
}

// ---------------------------------------------------------------------------
// fp32 -> bf16 convert (for weights), 4 elems/thread
// ---------------------------------------------------------------------------
__global__ void cvt_kernel(const float* __restrict__ in, u16* __restrict__ outp, int n4) {
    int i = blockIdx.x * 256 + threadIdx.x;
    if (i >= n4) return;
    float4 v = ((const float4*)in)[i];
    u16x4 o;
    o[0] = f2bf(v.x); o[1] = f2bf(v.y); o[2] = f2bf(v.z); o[3] = f2bf(v.w);
    ((u16x4*)outp)[i] = o;
}

// ---------------------------------------------------------------------------
// MFMA GEMM: C[m][n] = epilogue(sum_k A[m][k] * W[n][k] + bias[n])
// A (M,K) bf16 row-major (lda), W (N,K) bf16 row-major (ldb).
// 128x128 tile, BK=32, 4 waves (2x2 of 64x64), 16x16x32 MFMA.
// Batched over blockIdx.z: offset = (z>>3)*Zb + (z&7)*Zh for A,B,C.
// MODE: 0 = f32 out + bias
//       1 = bf16 out + bias
//       2 = bf16 out + bias + gelu
//       3 = f32 out, no bias, * 1/sqrt(128)
//       4 = bf16 out, no bias
// ---------------------------------------------------------------------------
template<int MODE>
__global__ void mfma_gemm(const u16* __restrict__ A, int lda, long aZb, long aZh,
                          const u16* __restrict__ Bw, int ldb, long bZb, long bZh,
                          void* __restrict__ Cout, int ldc, long cZb, long cZh,
                          const float* __restrict__ bias, int K) {
    __shared__ u16 As[128 * 32];
    __shared__ u16 Bs[128 * 32];
    int t = threadIdx.x;
    int w = t >> 6, lane = t & 63;
    int wr = w >> 1, wc = w & 1;
    int z = blockIdx.z, zb = z >> 3, zh = z & 7;
    const u16* Ab = A + (size_t)zb * aZb + (size_t)zh * aZh;
    const u16* Bb = Bw + (size_t)zb * bZb + (size_t)zh * bZh;
    int m0 = blockIdx.y * 128, n0 = blockIdx.x * 128;

    // staging chunk decomposition: chunk c -> row c>>2, col (c&3)*8 (16B)
    int c0 = t, c1 = t + 256;
    int r0 = c0 >> 2, q0 = (c0 & 3) * 8;
    int r1 = c1 >> 2, q1 = (c1 & 3) * 8;

    f32x4 acc[4][4] = {};

    for (int k0 = 0; k0 < K; k0 += 32) {
        gl_lds16(Ab + (size_t)(m0 + r0) * lda + k0 + q0, As + w * 512);
        gl_lds16(Ab + (size_t)(m0 + r1) * lda + k0 + q1, As + 2048 + w * 512);
        gl_lds16(Bb + (size_t)(n0 + r0) * ldb + k0 + q0, Bs + w * 512);
        gl_lds16(Bb + (size_t)(n0 + r1) * ldb + k0 + q1, Bs + 2048 + w * 512);
        __syncthreads();   // drains vmcnt -> LDS ready

        u16x8 af[4], bf[4];
        int koff = (lane >> 4) * 8;
        #pragma unroll
        for (int i = 0; i < 4; ++i)
            af[i] = *(const u16x8*)(As + (wr * 64 + i * 16 + (lane & 15)) * 32 + koff);
        #pragma unroll
        for (int j = 0; j < 4; ++j)
            bf[j] = *(const u16x8*)(Bs + (wc * 64 + j * 16 + (lane & 15)) * 32 + koff);
        #pragma unroll
        for (int i = 0; i < 4; ++i)
            #pragma unroll
            for (int j = 0; j < 4; ++j)
                acc[i][j] = mfma16(af[i], bf[j], acc[i][j]);
        __syncthreads();   // before next overwrite
    }

    // epilogue: C/D layout col=lane&15, row=(lane>>4)*4+r
    size_t cOff = (size_t)zb * cZb + (size_t)zh * cZh;
    #pragma unroll
    for (int i = 0; i < 4; ++i) {
        int rowb = m0 + wr * 64 + i * 16 + (lane >> 4) * 4;
        #pragma unroll
        for (int j = 0; j < 4; ++j) {
            int col = n0 + wc * 64 + j * 16 + (lane & 15);
            float bv = (MODE == 0 || MODE == 1 || MODE == 2) ? bias[col] : 0.f;
            #pragma unroll
            for (int r = 0; r < 4; ++r) {
                float v = acc[i][j][r] + bv;
                size_t idx = cOff + (size_t)(rowb + r) * ldc + col;
                if (MODE == 0) {
                    ((float*)Cout)[idx] = v;
                } else if (MODE == 1) {
                    ((u16*)Cout)[idx] = f2bf(v);
                } else if (MODE == 2) {
                    ((u16*)Cout)[idx] = f2bf(gelu_exact(v));
                } else if (MODE == 3) {
                    ((float*)Cout)[idx] = v * 0.08838834764831844f;
                } else {
                    ((u16*)Cout)[idx] = f2bf(v);
                }
            }
        }
    }
}

// ---------------------------------------------------------------------------
// V transpose: Vt[z][d][l] = qkv_bf[b*L+l][2D + h*128 + d], 64x64 LDS tiles
// ---------------------------------------------------------------------------
__global__ void transpose_v(const u16* __restrict__ qkv_bf, u16* __restrict__ Vt) {
    int z = blockIdx.z, b = z >> 3, h = z & 7;
    int l0 = blockIdx.x * 64, d0 = blockIdx.y * 64;
    __shared__ u16 tile[64][72];
    int t = threadIdx.x;
    #pragma unroll
    for (int i = 0; i < 2; ++i) {
        int c = i * 256 + t;
        int l = c >> 3, d8 = (c & 7) * 8;
        const u16* src = qkv_bf + (size_t)(b * L + l0 + l) * (3 * D) + 2 * D + h * HD + d0 + d8;
        *(u16x8*)&tile[l][d8] = *(const u16x8*)src;
    }
    __syncthreads();
    #pragma unroll
    for (int i = 0; i < 2; ++i) {
        int c = i * 256 + t;
        int d = c >> 3, l8 = (c & 7) * 8;
        u16x8 v;
        #pragma unroll
        for (int j = 0; j < 8; ++j) v[j] = tile[l8 + j][d];
        *(u16x8*)&Vt[((size_t)z * HD + d0 + d) * L + l0 + l8] = v;
    }
}

// ---------------------------------------------------------------------------
// Row softmax in place (fp32) + bf16 copy for PV
// ---------------------------------------------------------------------------
__global__ void softmax_kernel(float* __restrict__ p, u16* __restrict__ pbf) {
    size_t row = blockIdx.x;
    float* r = p + row * L;
    u16* rb = pbf + row * L;
    int t = threadIdx.x;
    float a = r[t], b = r[t + 256];
    __shared__ float red[256];
    red[t] = fmaxf(a, b);
    __syncthreads();
    for (int s = 128; s > 0; s >>= 1) {
        if (t < s) red[t] = fmaxf(red[t], red[t+s]);
        __syncthreads();
    }
    float m = red[0];
    __syncthreads();
    float e0 = expf(a - m), e1 = expf(b - m);
    red[t] = e0 + e1;
    __syncthreads();
    for (int s = 128; s > 0; s >>= 1) {
        if (t < s) red[t] += red[t+s];
        __syncthreads();
    }
    float inv = 1.0f / red[0];
    float p0 = e0 * inv, p1 = e1 * inv;
    r[t] = p0;
    r[t + 256] = p1;
    rb[t] = f2bf(p0);
    rb[t + 256] = f2bf(p1);
}

// ---------------------------------------------------------------------------
// Fused residual add + LayerNorm: out = LN(x + y) * g + b (fp32 + bf16 out)
// ---------------------------------------------------------------------------
__global__ void ln_add_kernel(const float* __restrict__ xin,
                              const float* __restrict__ yin,
                              float* __restrict__ xout,
                              u16* __restrict__ xbf,
                              const float* __restrict__ g,
                              const float* __restrict__ bta) {
    int row = blockIdx.x;
    int t = threadIdx.x;
    const float* xr = xin + (size_t)row * D;
    const float* yr = yin + (size_t)row * D;
    float4 xv = *(const float4*)&xr[t*4];
    float4 yv = *(const float4*)&yr[t*4];
    float s0 = xv.x + yv.x, s1 = xv.y + yv.y, s2 = xv.z + yv.z, s3 = xv.w + yv.w;
    __shared__ float red[256];
    red[t] = s0 + s1 + s2 + s3;
    __syncthreads();
    for (int st = 128; st > 0; st >>= 1) {
        if (t < st) red[t] += red[t+st];
        __syncthreads();
    }
    float mean = red[0] * (1.0f / (float)D);
    __syncthreads();
    float d0 = s0 - mean, d1 = s1 - mean, d2 = s2 - mean, d3 = s3 - mean;
    red[t] = d0*d0 + d1*d1 + d2*d2 + d3*d3;
    __syncthreads();
    for (int st = 128; st > 0; st >>= 1) {
        if (t < st) red[t] += red[t+st];
        __syncthreads();
    }
    float rstd = rsqrtf(red[0] * (1.0f / (float)D) + 1e-5f);
    float4 gv = *(const float4*)&g[t*4];
    float4 bv = *(const float4*)&bta[t*4];
    float4 o;
    o.x = d0 * rstd * gv.x + bv.x;
    o.y = d1 * rstd * gv.y + bv.y;
    o.z = d2 * rstd * gv.z + bv.z;
    o.w = d3 * rstd * gv.w + bv.w;
    *(float4*)&(xout + (size_t)row * D)[t*4] = o;
    u16* xb = xbf + (size_t)row * D + t*4;
    xb[0] = f2bf(o.x); xb[1] = f2bf(o.y); xb[2] = f2bf(o.z); xb[3] = f2bf(o.w);
}

// ---------------------------------------------------------------------------
// Head: logits[b][a] = dot(x[b*L+511], pred_w[a]) + pred_b[a]
// ---------------------------------------------------------------------------
__global__ void logits_kernel(const float* __restrict__ x,
                              const float* __restrict__ pw,
                              const float* __restrict__ pb,
                              float* __restrict__ lbuf) {
    int ba = blockIdx.x;           // 0..39
    int b = ba / NA, a = ba % NA;
    const float* xr = x + ((size_t)(b * L + (L-1))) * D;
    const float* wr = pw + (size_t)a * D;
    float s = 0.f;
    for (int k = threadIdx.x; k < D; k += 256) s += xr[k] * wr[k];
    __shared__ float red[256];
    int t = threadIdx.x;
    red[t] = s;
    __syncthreads();
    for (int st = 128; st > 0; st >>= 1) {
        if (t < st) red[t] += red[t+st];
        __syncthreads();
    }
    if (t == 0) lbuf[ba] = red[0] + pb[a];
}

// ---------------------------------------------------------------------------
// Loss + acc (tiny, single thread)
// ---------------------------------------------------------------------------
__global__ void loss_kernel(const float* __restrict__ lbuf,
                            const int* __restrict__ tgt,
                            float* __restrict__ out) {
    if (threadIdx.x != 0 || blockIdx.x != 0) return;
    float loss = 0.f, acc = 0.f;
    for (int b = 0; b < B; ++b) {
        const float* lg = lbuf + b * NA;
        float mx = lg[0]; int am = 0;
        for (int a = 1; a < NA; ++a) if (lg[a] > mx) { mx = lg[a]; am = a; }
        float se = 0.f;
        for (int a = 0; a < NA; ++a) se += expf(lg[a] - mx);
        float lse = mx + logf(se);
        float mean_lp = 0.f;
        for (int a = 0; a < NA; ++a) mean_lp += (lg[a] - lse);
        mean_lp *= (1.0f / NA);
        int tb = tgt[b];
        float nll = -(lg[tb] - lse);
        loss += 0.9f * nll - 0.1f * mean_lp;
        acc += (am == tb) ? 1.f : 0.f;
    }
    out[0] = loss * (1.0f / B);
    out[1] = acc * (1.0f / B);
}

// ---------------------------------------------------------------------------
extern "C" void kernel_launch(void* const* d_in, const int* in_sizes, int n_in,
                              void* d_out, int out_size, void* d_ws, size_t ws_size,
                              hipStream_t stream) {
    const float* states      = (const float*)d_in[0];
    const float* actions     = (const float*)d_in[1];
    const float* next_states = (const float*)d_in[2];
    const float* rewards     = (const float*)d_in[3];
    const float* pos         = (const float*)d_in[4];
    const float* ecw         = (const float*)d_in[5];
    const float* ecb         = (const float*)d_in[6];
    const float* table       = (const float*)d_in[7];
    const float* in_proj_w   = (const float*)d_in[8];
    const float* in_proj_b   = (const float*)d_in[9];
    const float* out_proj_w  = (const float*)d_in[10];
    const float* out_proj_b  = (const float*)d_in[11];
    const float* linear1_w   = (const float*)d_in[12];
    const float* linear1_b   = (const float*)d_in[13];
    const float* linear2_w   = (const float*)d_in[14];
    const float* linear2_b   = (const float*)d_in[15];
    const float* norm1_g     = (const float*)d_in[16];
    const float* norm1_b     = (const float*)d_in[17];
    const float* norm2_g     = (const float*)d_in[18];
    const float* norm2_b     = (const float*)d_in[19];
    const float* pred_w      = (const float*)d_in[20];
    const float* pred_b      = (const float*)d_in[21];
    const int*   query_states   = (const int*)d_in[22];
    const int*   target_actions = (const int*)d_in[23];

    float* out = (float*)d_out;

    // ---- workspace layout (byte offsets) ----
    char* W = (char*)d_ws;
    float* x      = (float*)(W + 0);                 // 16 MB   (ML*D f32)
    u16*   x_bf   = (u16*)  (W + 16777216);          //  8 MB   (ML*D bf16)
    u16*   win_bf = (u16*)  (W + 25165824);          //  6 MB   (3072*1024)
    u16*   wout_bf= (u16*)  (W + 31457280);          //  2 MB   (1024*1024)
    u16*   wl1_bf = (u16*)  (W + 33554432);          //  8 MB   (4096*1024)
    u16*   wl2_bf = (u16*)  (W + 41943040);          //  8 MB   (1024*4096)
    // unionA region: {qkv_bf + Vt} OR {ff_bf}
    u16*   qkv_bf = (u16*)  (W + 50331648);          // 24 MB   (ML*3072)
    u16*   Vt     = (u16*)  (W + 75497472);          //  8 MB   (64*128*512)
    u16*   ff_bf  = (u16*)  (W + 50331648);          // 32 MB   (ML*DFF) aliases qkv+Vt
    u16*   P_bf   = (u16*)  (W + 83886080);          // 32 MB   (64*512*512)
    u16*   ctx_bf = (u16*)  (W + 117440512);         //  8 MB   (ML*D)
    float* fbuf   = (float*)(W + 125829120);         // 16 MB   (ML*D f32)
    float* lbuf   = (float*)(W + 142606336);         // logits (40)

    embed_kernel<<<(ML * D) / 256, 256, 0, stream>>>(
        states, actions, next_states, rewards, pos, ecw, ecb, table,
        query_states, x, x_bf);

    // weight conversions (once per call; weights shared across layers)
    cvt_kernel<<<(3072*1024/4 + 255)/256, 256, 0, stream>>>(in_proj_w,  win_bf,  3072*1024/4);
    cvt_kernel<<<(1024*1024/4 + 255)/256, 256, 0, stream>>>(out_proj_w, wout_bf, 1024*1024/4);
    cvt_kernel<<<(4096*1024/4 + 255)/256, 256, 0, stream>>>(linear1_w,  wl1_bf,  4096*1024/4);
    cvt_kernel<<<(1024*4096/4 + 255)/256, 256, 0, stream>>>(linear2_w,  wl2_bf,  1024*4096/4);

    const long LL = (long)L * L;          // 262144
    for (int l = 0; l < NLAYERS; ++l) {
        float* attnL = out + 2 + (size_t)l * B * H * LL;

        // qkv = x @ in_proj_w^T + b  -> bf16 (4096,3072)
        mfma_gemm<1><<<dim3(3072/128, ML/128, 1), 256, 0, stream>>>(
            x_bf, D, 0, 0, win_bf, D, 0, 0, qkv_bf, 3*D, 0, 0, in_proj_b, D);

        // Vt[z][d][l]
        transpose_v<<<dim3(8, 2, B*H), 256, 0, stream>>>(qkv_bf, Vt);

        // scores: per z (b,h): (512,512) = Q Kt * scale -> fp32 into attn slice
        mfma_gemm<3><<<dim3(L/128, L/128, B*H), 256, 0, stream>>>(
            qkv_bf,        3*D, (long)L*3*D, HD,
            qkv_bf + D,    3*D, (long)L*3*D, HD,
            attnL,         L,   (long)H*LL,  LL,
            nullptr, HD);

        // softmax in place + bf16 copy
        softmax_kernel<<<B*H*L, 256, 0, stream>>>(attnL, P_bf);

        // PV: per z: (512,128) = P @ V -> ctx bf16 at col h*128
        mfma_gemm<4><<<dim3(HD/128, L/128, B*H), 256, 0, stream>>>(
            P_bf, L, (long)H*LL, LL,
            Vt,   L, (long)H*HD*L, (long)HD*L,
            ctx_bf, D, (long)L*D, HD,
            nullptr, L);

        // out_proj -> fp32
        mfma_gemm<0><<<dim3(D/128, ML/128, 1), 256, 0, stream>>>(
            ctx_bf, D, 0, 0, wout_bf, D, 0, 0, fbuf, D, 0, 0, out_proj_b, D);

        // x = LN(x + proj)  (+ bf16 copy)
        ln_add_kernel<<<ML, 256, 0, stream>>>(x, fbuf, x, x_bf, norm1_g, norm1_b);

        // ff1 + gelu -> bf16 (4096,4096)
        mfma_gemm<2><<<dim3(DFF/128, ML/128, 1), 256, 0, stream>>>(
            x_bf, D, 0, 0, wl1_bf, D, 0, 0, ff_bf, DFF, 0, 0, linear1_b, D);

        // ff2 -> fp32
        mfma_gemm<0><<<dim3(D/128, ML/128, 1), 256, 0, stream>>>(
            ff_bf, DFF, 0, 0, wl2_bf, DFF, 0, 0, fbuf, D, 0, 0, linear2_b, DFF);

        // x = LN(x + ff)  (+ bf16 copy)
        ln_add_kernel<<<ML, 256, 0, stream>>>(x, fbuf, x, x_bf, norm2_g, norm2_b);
    }

    logits_kernel<<<B*NA, 256, 0, stream>>>(x, pred_w, pred_b, lbuf);
    loss_kernel<<<1, 64, 0, stream>>>(lbuf, target_actions, out);
}

// Round 3
// 1255.644 us; speedup vs baseline: 6.9832x; 1.0081x over previous
//
#include <hip/hip_runtime.h>
#include <hip/hip_bf16.h>
#include <math.h>

// Problem constants
#define B  8
#define NN 511
#define L  512          // n_transit
#define D  1024
#define DFF 4096
#define H  8
#define HD 128
#define NA 5
#define NLAYERS 4
#define ML (B*L)        // 4096 rows

typedef unsigned short u16;
typedef float f32x4 __attribute__((ext_vector_type(4)));
typedef u16   u16x8 __attribute__((ext_vector_type(8)));
typedef u16   u16x4 __attribute__((ext_vector_type(4)));
typedef __bf16 b16x8 __attribute__((ext_vector_type(8)));

__device__ __forceinline__ u16 f2bf(float f) {
    __hip_bfloat16 h = __float2bfloat16(f);
    return __builtin_bit_cast(u16, h);
}
__device__ __forceinline__ float bf2f(u16 u) {
    return __builtin_bit_cast(float, (unsigned)u << 16);
}

__device__ __forceinline__ float gelu_exact(float v) {
    return 0.5f * v * (1.0f + erff(v * 0.70710678118654752440f));
}

__device__ __forceinline__ f32x4 mfma16(u16x8 a, u16x8 b, f32x4 c) {
    return __builtin_amdgcn_mfma_f32_16x16x32_bf16(
        __builtin_bit_cast(b16x8, a), __builtin_bit_cast(b16x8, b), c, 0, 0, 0);
}

__device__ __forceinline__ void gl_lds16(const u16* g, u16* l) {
    __builtin_amdgcn_global_load_lds(
        (const __attribute__((address_space(1))) unsigned int*)g,
        (__attribute__((address_space(3))) unsigned int*)l,
        16, 0, 0);
}

// ---------------------------------------------------------------------------
// Embedding
// ---------------------------------------------------------------------------
__global__ void embed_kernel(const float* __restrict__ states,
                             const float* __restrict__ actions,
                             const float* __restrict__ next_states,
                             const float* __restrict__ rewards,
                             const float* __restrict__ pos,
                             const float* __restrict__ ecw,   // (1024,10)
                             const float* __restrict__ ecb,   // (1024)
                             const float* __restrict__ table, // (81,1024)
                             const int*   __restrict__ qs,    // (8,2)
                             float* __restrict__ x,
                             u16* __restrict__ xbf) {
    size_t gid = (size_t)blockIdx.x * 256 + threadIdx.x;
    int d   = (int)(gid & (D - 1));
    int row = (int)(gid >> 10);
    int t = row & (L - 1);
    int b = row >> 9;
    float v;
    if (t < NN) {
        const float* w = ecw + (size_t)d * 10;
        int st = b * NN + t;
        float acc = ecb[d];
        acc += states[st*2+0]*w[0] + states[st*2+1]*w[1];
        acc += actions[st*5+0]*w[2] + actions[st*5+1]*w[3] + actions[st*5+2]*w[4]
             + actions[st*5+3]*w[5] + actions[st*5+4]*w[6];
        acc += rewards[st]*w[7];
        acc += next_states[st*2+0]*w[8] + next_states[st*2+1]*w[9];
        v = acc;
    } else {
        int qi = qs[b*2+0] * 9 + qs[b*2+1];
        v = table[(size_t)qi * D + d];
    }
    float o = v + pos[(size_t)t * D + d];
    x[(size_t)row * D + d] = o;
    xbf[(size_t)row * D + d] = f2bf(o);
}

// ---------------------------------------------------------------------------
__global__ void cvt_kernel(const float* __restrict__ in, u16* __restrict__ outp, int n4) {
    int i = blockIdx.x * 256 + threadIdx.x;
    if (i >= n4) return;
    float4 v = ((const float4*)in)[i];
    u16x4 o;
    o[0] = f2bf(v.x); o[1] = f2bf(v.y); o[2] = f2bf(v.z); o[3] = f2bf(v.w);
    ((u16x4*)outp)[i] = o;
}

// ---------------------------------------------------------------------------
// MFMA GEMM (unchanged from round 2): 128x128 tile, BK=32, 4 waves.
// MODE: 0 = f32 out + bias, 1 = bf16 out + bias, 2 = bf16 out + bias + gelu
// ---------------------------------------------------------------------------
template<int MODE>
__global__ void mfma_gemm(const u16* __restrict__ A, int lda, long aZb, long aZh,
                          const u16* __restrict__ Bw, int ldb, long bZb, long bZh,
                          void* __restrict__ Cout, int ldc, long cZb, long cZh,
                          const float* __restrict__ bias, int K) {
    __shared__ u16 As[128 * 32];
    __shared__ u16 Bs[128 * 32];
    int t = threadIdx.x;
    int w = t >> 6, lane = t & 63;
    int wr = w >> 1, wc = w & 1;
    int z = blockIdx.z, zb = z >> 3, zh = z & 7;
    const u16* Ab = A + (size_t)zb * aZb + (size_t)zh * aZh;
    const u16* Bb = Bw + (size_t)zb * bZb + (size_t)zh * bZh;
    int m0 = blockIdx.y * 128, n0 = blockIdx.x * 128;

    int c0 = t, c1 = t + 256;
    int r0 = c0 >> 2, q0 = (c0 & 3) * 8;
    int r1 = c1 >> 2, q1 = (c1 & 3) * 8;

    f32x4 acc[4][4] = {};

    for (int k0 = 0; k0 < K; k0 += 32) {
        gl_lds16(Ab + (size_t)(m0 + r0) * lda + k0 + q0, As + w * 512);
        gl_lds16(Ab + (size_t)(m0 + r1) * lda + k0 + q1, As + 2048 + w * 512);
        gl_lds16(Bb + (size_t)(n0 + r0) * ldb + k0 + q0, Bs + w * 512);
        gl_lds16(Bb + (size_t)(n0 + r1) * ldb + k0 + q1, Bs + 2048 + w * 512);
        __syncthreads();

        u16x8 af[4], bf[4];
        int koff = (lane >> 4) * 8;
        #pragma unroll
        for (int i = 0; i < 4; ++i)
            af[i] = *(const u16x8*)(As + (wr * 64 + i * 16 + (lane & 15)) * 32 + koff);
        #pragma unroll
        for (int j = 0; j < 4; ++j)
            bf[j] = *(const u16x8*)(Bs + (wc * 64 + j * 16 + (lane & 15)) * 32 + koff);
        #pragma unroll
        for (int i = 0; i < 4; ++i)
            #pragma unroll
            for (int j = 0; j < 4; ++j)
                acc[i][j] = mfma16(af[i], bf[j], acc[i][j]);
        __syncthreads();
    }

    size_t cOff = (size_t)zb * cZb + (size_t)zh * cZh;
    #pragma unroll
    for (int i = 0; i < 4; ++i) {
        int rowb = m0 + wr * 64 + i * 16 + (lane >> 4) * 4;
        #pragma unroll
        for (int j = 0; j < 4; ++j) {
            int col = n0 + wc * 64 + j * 16 + (lane & 15);
            float bv = bias[col];
            #pragma unroll
            for (int r = 0; r < 4; ++r) {
                float v = acc[i][j][r] + bv;
                size_t idx = cOff + (size_t)(rowb + r) * ldc + col;
                if (MODE == 0) {
                    ((float*)Cout)[idx] = v;
                } else if (MODE == 1) {
                    ((u16*)Cout)[idx] = f2bf(v);
                } else {
                    ((u16*)Cout)[idx] = f2bf(gelu_exact(v));
                }
            }
        }
    }
}

// ---------------------------------------------------------------------------
// V transpose: Vt[z][d][l]
// ---------------------------------------------------------------------------
__global__ void transpose_v(const u16* __restrict__ qkv_bf, u16* __restrict__ Vt) {
    int z = blockIdx.z, b = z >> 3, h = z & 7;
    int l0 = blockIdx.x * 64, d0 = blockIdx.y * 64;
    __shared__ u16 tile[64][72];
    int t = threadIdx.x;
    #pragma unroll
    for (int i = 0; i < 2; ++i) {
        int c = i * 256 + t;
        int l = c >> 3, d8 = (c & 7) * 8;
        const u16* src = qkv_bf + (size_t)(b * L + l0 + l) * (3 * D) + 2 * D + h * HD + d0 + d8;
        *(u16x8*)&tile[l][d8] = *(const u16x8*)src;
    }
    __syncthreads();
    #pragma unroll
    for (int i = 0; i < 2; ++i) {
        int c = i * 256 + t;
        int d = c >> 3, l8 = (c & 7) * 8;
        u16x8 v;
        #pragma unroll
        for (int j = 0; j < 8; ++j) v[j] = tile[l8 + j][d];
        *(u16x8*)&Vt[((size_t)z * HD + d0 + d) * L + l0 + l8] = v;
    }
}

// ---------------------------------------------------------------------------
// Fused attention: per block = one (b,h) x 32 Q-rows.
// S = QK^T (MFMA, frags direct from global), full-row softmax in-register,
// P -> swizzled LDS (bf16), coalesced fp32 P write to d_out, PV MFMA.
// ---------------------------------------------------------------------------
__global__ __launch_bounds__(256, 4) void fused_attn(
        const u16* __restrict__ qkv, const u16* __restrict__ Vt,
        float* __restrict__ attnL, u16* __restrict__ ctx) {
    __shared__ u16 Plds[32 * 512];          // 32 KB, XOR-swizzled
    __shared__ float red[4][32];
    int t = threadIdx.x;
    int w = t >> 6, lane = t & 63;
    int c = lane & 15, g = lane >> 4;
    int bh = blockIdx.y, b = bh >> 3, h = bh & 7;
    int q0 = blockIdx.x * 32;

    // --- Q fragments (2 row-tiles x 4 k-steps), direct from global ---
    const u16* Qb = qkv + ((size_t)(b * L + q0)) * (3*D) + h * HD;
    u16x8 qf[2][4];
    #pragma unroll
    for (int i = 0; i < 2; ++i)
        #pragma unroll
        for (int ks = 0; ks < 4; ++ks)
            qf[i][ks] = *(const u16x8*)(Qb + (size_t)(i*16 + c) * (3*D) + ks*32 + g*8);

    // --- S = Q K^T : wave w owns score cols [w*128, w*128+128) ---
    const u16* Kb = qkv + ((size_t)(b * L + w * 128)) * (3*D) + D + h * HD;
    f32x4 s[2][8];
    #pragma unroll
    for (int i = 0; i < 2; ++i)
        #pragma unroll
        for (int j = 0; j < 8; ++j)
            s[i][j] = (f32x4){0.f, 0.f, 0.f, 0.f};

    #pragma unroll
    for (int j = 0; j < 8; ++j) {
        u16x8 kf[4];
        #pragma unroll
        for (int ks = 0; ks < 4; ++ks)
            kf[ks] = *(const u16x8*)(Kb + (size_t)(j*16 + c) * (3*D) + ks*32 + g*8);
        #pragma unroll
        for (int i = 0; i < 2; ++i)
            #pragma unroll
            for (int ks = 0; ks < 4; ++ks)
                s[i][j] = mfma16(qf[i][ks], kf[ks], s[i][j]);
    }

    // --- softmax over full rows (512) ---
    // per-thread rows: row = i*16 + g*4 + r
    float mx[2][4];
    #pragma unroll
    for (int i = 0; i < 2; ++i)
        #pragma unroll
        for (int r = 0; r < 4; ++r) {
            float m = s[i][0][r];
            #pragma unroll
            for (int j = 1; j < 8; ++j) m = fmaxf(m, s[i][j][r]);
            #pragma unroll
            for (int msk = 1; msk < 16; msk <<= 1)
                m = fmaxf(m, __shfl_xor(m, msk));
            mx[i][r] = m;
        }
    if (c == 0) {
        #pragma unroll
        for (int i = 0; i < 2; ++i)
            #pragma unroll
            for (int r = 0; r < 4; ++r)
                red[w][i*16 + g*4 + r] = mx[i][r];
    }
    __syncthreads();
    float M[2][4];
    #pragma unroll
    for (int i = 0; i < 2; ++i)
        #pragma unroll
        for (int r = 0; r < 4; ++r) {
            int row = i*16 + g*4 + r;
            M[i][r] = fmaxf(fmaxf(red[0][row], red[1][row]),
                            fmaxf(red[2][row], red[3][row]));
        }
    __syncthreads();

    const float KC = 0.08838834764831844f * 1.4426950408889634f; // scale*log2e
    float sm[2][4];
    #pragma unroll
    for (int i = 0; i < 2; ++i)
        #pragma unroll
        for (int r = 0; r < 4; ++r) {
            float acc = 0.f;
            #pragma unroll
            for (int j = 0; j < 8; ++j) {
                float e = exp2f((s[i][j][r] - M[i][r]) * KC);
                s[i][j][r] = e;
                acc += e;
            }
            #pragma unroll
            for (int msk = 1; msk < 16; msk <<= 1)
                acc += __shfl_xor(acc, msk);
            sm[i][r] = acc;
        }
    if (c == 0) {
        #pragma unroll
        for (int i = 0; i < 2; ++i)
            #pragma unroll
            for (int r = 0; r < 4; ++r)
                red[w][i*16 + g*4 + r] = sm[i][r];
    }
    __syncthreads();
    float inv[2][4];
    #pragma unroll
    for (int i = 0; i < 2; ++i)
        #pragma unroll
        for (int r = 0; r < 4; ++r) {
            int row = i*16 + g*4 + r;
            inv[i][r] = 1.0f / (red[0][row] + red[1][row] + red[2][row] + red[3][row]);
        }

    // --- P -> LDS (bf16, swizzled: byte ^= (row&7)<<4) ---
    char* Pb = (char*)Plds;
    #pragma unroll
    for (int i = 0; i < 2; ++i)
        #pragma unroll
        for (int r = 0; r < 4; ++r) {
            int row = i*16 + g*4 + r;
            int sw = (row & 7) << 4;
            #pragma unroll
            for (int j = 0; j < 8; ++j) {
                int col = w*128 + j*16 + c;
                int a = (row << 10) + (col << 1);
                *(u16*)(Pb + (a ^ sw)) = f2bf(s[i][j][r] * inv[i][r]);
            }
        }
    __syncthreads();

    // --- coalesced fp32 P write to d_out (read back from LDS) ---
    {
        int row = t >> 3;
        int cb = (t & 7) * 128;             // byte offset within row
        int sw = (row & 7) << 4;
        float* dst = attnL + (size_t)bh * L * L + (size_t)(q0 + row) * L + (t & 7) * 64;
        #pragma unroll
        for (int u = 0; u < 8; ++u) {
            u16x8 v = *(const u16x8*)(Pb + (((row << 10) + cb + u*16) ^ sw));
            float4 lo, hi;
            lo.x = bf2f(v[0]); lo.y = bf2f(v[1]); lo.z = bf2f(v[2]); lo.w = bf2f(v[3]);
            hi.x = bf2f(v[4]); hi.y = bf2f(v[5]); hi.z = bf2f(v[6]); hi.w = bf2f(v[7]);
            ((float4*)dst)[u*2+0] = lo;
            ((float4*)dst)[u*2+1] = hi;
        }
    }

    // --- PV: wave w owns output cols [w*32, w*32+32) ---
    const u16* Vb = Vt + ((size_t)bh * HD + w * 32) * L;
    f32x4 o[2][2];
    #pragma unroll
    for (int i = 0; i < 2; ++i)
        #pragma unroll
        for (int j = 0; j < 2; ++j)
            o[i][j] = (f32x4){0.f, 0.f, 0.f, 0.f};

    #pragma unroll
    for (int ks = 0; ks < 16; ++ks) {
        u16x8 aP[2];
        #pragma unroll
        for (int i = 0; i < 2; ++i) {
            int row = i*16 + c;
            int a = (row << 10) + ks*64 + g*16;
            aP[i] = *(const u16x8*)(Pb + (a ^ ((row & 7) << 4)));
        }
        u16x8 vf[2];
        #pragma unroll
        for (int j = 0; j < 2; ++j)
            vf[j] = *(const u16x8*)(Vb + (size_t)(j*16 + c) * L + ks*32 + g*8);
        #pragma unroll
        for (int i = 0; i < 2; ++i)
            #pragma unroll
            for (int j = 0; j < 2; ++j)
                o[i][j] = mfma16(aP[i], vf[j], o[i][j]);
    }

    #pragma unroll
    for (int i = 0; i < 2; ++i)
        #pragma unroll
        for (int j = 0; j < 2; ++j)
            #pragma unroll
            for (int r = 0; r < 4; ++r) {
                int row = q0 + i*16 + g*4 + r;
                int col = h*HD + w*32 + j*16 + c;
                ctx[(size_t)(b * L + row) * D + col] = f2bf(o[i][j][r]);
            }
}

// ---------------------------------------------------------------------------
// Fused residual add + LayerNorm (fp32 + bf16 out)
// ---------------------------------------------------------------------------
__global__ void ln_add_kernel(const float* __restrict__ xin,
                              const float* __restrict__ yin,
                              float* __restrict__ xout,
                              u16* __restrict__ xbf,
                              const float* __restrict__ g,
                              const float* __restrict__ bta) {
    int row = blockIdx.x;
    int t = threadIdx.x;
    const float* xr = xin + (size_t)row * D;
    const float* yr = yin + (size_t)row * D;
    float4 xv = *(const float4*)&xr[t*4];
    float4 yv = *(const float4*)&yr[t*4];
    float s0 = xv.x + yv.x, s1 = xv.y + yv.y, s2 = xv.z + yv.z, s3 = xv.w + yv.w;
    __shared__ float red[256];
    red[t] = s0 + s1 + s2 + s3;
    __syncthreads();
    for (int st = 128; st > 0; st >>= 1) {
        if (t < st) red[t] += red[t+st];
        __syncthreads();
    }
    float mean = red[0] * (1.0f / (float)D);
    __syncthreads();
    float d0 = s0 - mean, d1 = s1 - mean, d2 = s2 - mean, d3 = s3 - mean;
    red[t] = d0*d0 + d1*d1 + d2*d2 + d3*d3;
    __syncthreads();
    for (int st = 128; st > 0; st >>= 1) {
        if (t < st) red[t] += red[t+st];
        __syncthreads();
    }
    float rstd = rsqrtf(red[0] * (1.0f / (float)D) + 1e-5f);
    float4 gv = *(const float4*)&g[t*4];
    float4 bv = *(const float4*)&bta[t*4];
    float4 o;
    o.x = d0 * rstd * gv.x + bv.x;
    o.y = d1 * rstd * gv.y + bv.y;
    o.z = d2 * rstd * gv.z + bv.z;
    o.w = d3 * rstd * gv.w + bv.w;
    *(float4*)&(xout + (size_t)row * D)[t*4] = o;
    u16* xb = xbf + (size_t)row * D + t*4;
    xb[0] = f2bf(o.x); xb[1] = f2bf(o.y); xb[2] = f2bf(o.z); xb[3] = f2bf(o.w);
}

// ---------------------------------------------------------------------------
__global__ void logits_kernel(const float* __restrict__ x,
                              const float* __restrict__ pw,
                              const float* __restrict__ pb,
                              float* __restrict__ lbuf) {
    int ba = blockIdx.x;
    int b = ba / NA, a = ba % NA;
    const float* xr = x + ((size_t)(b * L + (L-1))) * D;
    const float* wr = pw + (size_t)a * D;
    float s = 0.f;
    for (int k = threadIdx.x; k < D; k += 256) s += xr[k] * wr[k];
    __shared__ float red[256];
    int t = threadIdx.x;
    red[t] = s;
    __syncthreads();
    for (int st = 128; st > 0; st >>= 1) {
        if (t < st) red[t] += red[t+st];
        __syncthreads();
    }
    if (t == 0) lbuf[ba] = red[0] + pb[a];
}

__global__ void loss_kernel(const float* __restrict__ lbuf,
                            const int* __restrict__ tgt,
                            float* __restrict__ out) {
    if (threadIdx.x != 0 || blockIdx.x != 0) return;
    float loss = 0.f, acc = 0.f;
    for (int b = 0; b < B; ++b) {
        const float* lg = lbuf + b * NA;
        float mx = lg[0]; int am = 0;
        for (int a = 1; a < NA; ++a) if (lg[a] > mx) { mx = lg[a]; am = a; }
        float se = 0.f;
        for (int a = 0; a < NA; ++a) se += expf(lg[a] - mx);
        float lse = mx + logf(se);
        float mean_lp = 0.f;
        for (int a = 0; a < NA; ++a) mean_lp += (lg[a] - lse);
        mean_lp *= (1.0f / NA);
        int tb = tgt[b];
        float nll = -(lg[tb] - lse);
        loss += 0.9f * nll - 0.1f * mean_lp;
        acc += (am == tb) ? 1.f : 0.f;
    }
    out[0] = loss * (1.0f / B);
    out[1] = acc * (1.0f / B);
}

// ---------------------------------------------------------------------------
extern "C" void kernel_launch(void* const* d_in, const int* in_sizes, int n_in,
                              void* d_out, int out_size, void* d_ws, size_t ws_size,
                              hipStream_t stream) {
    const float* states      = (const float*)d_in[0];
    const float* actions     = (const float*)d_in[1];
    const float* next_states = (const float*)d_in[2];
    const float* rewards     = (const float*)d_in[3];
    const float* pos         = (const float*)d_in[4];
    const float* ecw         = (const float*)d_in[5];
    const float* ecb         = (const float*)d_in[6];
    const float* table       = (const float*)d_in[7];
    const float* in_proj_w   = (const float*)d_in[8];
    const float* in_proj_b   = (const float*)d_in[9];
    const float* out_proj_w  = (const float*)d_in[10];
    const float* out_proj_b  = (const float*)d_in[11];
    const float* linear1_w   = (const float*)d_in[12];
    const float* linear1_b   = (const float*)d_in[13];
    const float* linear2_w   = (const float*)d_in[14];
    const float* linear2_b   = (const float*)d_in[15];
    const float* norm1_g     = (const float*)d_in[16];
    const float* norm1_b     = (const float*)d_in[17];
    const float* norm2_g     = (const float*)d_in[18];
    const float* norm2_b     = (const float*)d_in[19];
    const float* pred_w      = (const float*)d_in[20];
    const float* pred_b      = (const float*)d_in[21];
    const int*   query_states   = (const int*)d_in[22];
    const int*   target_actions = (const int*)d_in[23];

    float* out = (float*)d_out;

    // ---- workspace layout (byte offsets) ----
    char* W = (char*)d_ws;
    float* x      = (float*)(W + 0);                 // 16 MB
    u16*   x_bf   = (u16*)  (W + 16777216);          //  8 MB
    u16*   win_bf = (u16*)  (W + 25165824);          //  6 MB
    u16*   wout_bf= (u16*)  (W + 31457280);          //  2 MB
    u16*   wl1_bf = (u16*)  (W + 33554432);          //  8 MB
    u16*   wl2_bf = (u16*)  (W + 41943040);          //  8 MB
    u16*   qkv_bf = (u16*)  (W + 50331648);          // 24 MB
    u16*   Vt     = (u16*)  (W + 75497472);          //  8 MB
    u16*   ff_bf  = (u16*)  (W + 50331648);          // 32 MB (aliases qkv+Vt)
    u16*   ctx_bf = (u16*)  (W + 117440512);         //  8 MB
    float* fbuf   = (float*)(W + 125829120);         // 16 MB
    float* lbuf   = (float*)(W + 142606336);         // logits (40)

    embed_kernel<<<(ML * D) / 256, 256, 0, stream>>>(
        states, actions, next_states, rewards, pos, ecw, ecb, table,
        query_states, x, x_bf);

    cvt_kernel<<<(3072*1024/4 + 255)/256, 256, 0, stream>>>(in_proj_w,  win_bf,  3072*1024/4);
    cvt_kernel<<<(1024*1024/4 + 255)/256, 256, 0, stream>>>(out_proj_w, wout_bf, 1024*1024/4);
    cvt_kernel<<<(4096*1024/4 + 255)/256, 256, 0, stream>>>(linear1_w,  wl1_bf,  4096*1024/4);
    cvt_kernel<<<(1024*4096/4 + 255)/256, 256, 0, stream>>>(linear2_w,  wl2_bf,  1024*4096/4);

    const long LL = (long)L * L;
    for (int l = 0; l < NLAYERS; ++l) {
        float* attnL = out + 2 + (size_t)l * B * H * LL;

        // qkv = x @ in_proj_w^T + b  -> bf16 (4096,3072)
        mfma_gemm<1><<<dim3(3072/128, ML/128, 1), 256, 0, stream>>>(
            x_bf, D, 0, 0, win_bf, D, 0, 0, qkv_bf, 3*D, 0, 0, in_proj_b, D);

        // Vt[z][d][l]
        transpose_v<<<dim3(8, 2, B*H), 256, 0, stream>>>(qkv_bf, Vt);

        // fused scores + softmax + d_out P write + PV
        fused_attn<<<dim3(L/32, B*H), 256, 0, stream>>>(qkv_bf, Vt, attnL, ctx_bf);

        // out_proj -> fp32
        mfma_gemm<0><<<dim3(D/128, ML/128, 1), 256, 0, stream>>>(
            ctx_bf, D, 0, 0, wout_bf, D, 0, 0, fbuf, D, 0, 0, out_proj_b, D);

        ln_add_kernel<<<ML, 256, 0, stream>>>(x, fbuf, x, x_bf, norm1_g, norm1_b);

        // ff1 + gelu -> bf16 (4096,4096)
        mfma_gemm<2><<<dim3(DFF/128, ML/128, 1), 256, 0, stream>>>(
            x_bf, D, 0, 0, wl1_bf, D, 0, 0, ff_bf, DFF, 0, 0, linear1_b, D);

        // ff2 -> fp32
        mfma_gemm<0><<<dim3(D/128, ML/128, 1), 256, 0, stream>>>(
            ff_bf, DFF, 0, 0, wl2_bf, DFF, 0, 0, fbuf, D, 0, 0, linear2_b, DFF);

        ln_add_kernel<<<ML, 256, 0, stream>>>(x, fbuf, x, x_bf, norm2_g, norm2_b);
    }

    logits_kernel<<<B*NA, 256, 0, stream>>>(x, pred_w, pred_b, lbuf);
    loss_kernel<<<1, 64, 0, stream>>>(lbuf, target_actions, out);
}